// Round 6
// baseline (293.092 us; speedup 1.0000x reference)
//
#include <hip/hip_runtime.h>

#define NSAMP 32768
#define INF 512
#define OUTF 512
#define NB 8            // spline bases per input
#define KSP 4096        // INF * NB (spline columns)
#define KTOT 4608       // KSP + INF (silu columns)

typedef __attribute__((ext_vector_type(8))) short bf16x8;
typedef __attribute__((ext_vector_type(4))) float f32x4;

typedef __attribute__((address_space(1))) void gas_void;
typedef __attribute__((address_space(3))) void las_void;
#define GLL16(g, l) __builtin_amdgcn_global_load_lds( \
    (const gas_void*)(g), (las_void*)(l), 16, 0, 0)

// float -> bf16 round-nearest-even (W prep only)
__device__ __forceinline__ unsigned short f2bf(float f) {
  unsigned int u = __float_as_uint(f);
  u += 0x7fffu + ((u >> 16) & 1u);
  return (unsigned short)(u >> 16);
}

// pack two floats as bf16 pair (round-nearest-up). lo in low 16 bits.
__device__ __forceinline__ unsigned pack_rn(float lo, float hi) {
  return __builtin_amdgcn_perm(__float_as_uint(hi) + 0x8000u,
                               __float_as_uint(lo) + 0x8000u, 0x07060302u);
}

// 8-slot cubic B-spline basis vector, scaled by 6 (the 1/6 is folded into W).
// Branchless; out-of-grid x -> all-zero (matches reference clipping).
__device__ __forceinline__ uint4 kan_basis_vec(float xv) {
  float t = __builtin_fmaf(xv, 1.0f / 1.2f, 5.5f);   // (x+6.6)/1.2
  float cf = floorf(t);
  float u = t - cf;
  int j0 = (int)cf - 3;
  float omu = 1.0f - u;
  float u2 = u * u, u3 = u2 * u;
  float omu2 = omu * omu;
  float w0 = omu2 * omu;                                         // 6*(1/6)omu^3
  float w1 = __builtin_fmaf(3.f, u3, __builtin_fmaf(-6.f, u2, 4.f));
  float w2 = __builtin_fmaf(-3.f, u3,
              __builtin_fmaf(3.f, u2, __builtin_fmaf(3.f, u, 1.f)));
  float w3 = u3;
  unsigned P0 = pack_rn(w0, w1);
  unsigned P1 = pack_rn(w2, w3);
  // 128-bit result = [P1:P0] << (16*j0), bits outside [0,128) dropped.
  int p = j0 & 1;
  unsigned Q0 = p ? (P0 << 16) : P0;
  unsigned Q1 = p ? __builtin_amdgcn_alignbit(P1, P0, 16) : P1;
  unsigned Q2 = p ? (P1 >> 16) : 0u;
  int D = j0 >> 1;
  uint4 r;
  r.x = (D == 0) ? Q0 : (D == -1) ? Q1 : (D == -2) ? Q2 : 0u;
  r.y = (D == 1) ? Q0 : (D ==  0) ? Q1 : (D == -1) ? Q2 : 0u;
  r.z = (D == 2) ? Q0 : (D ==  1) ? Q1 : (D ==  0) ? Q2 : 0u;
  r.w = (D == 3) ? Q0 : (D ==  2) ? Q1 : (D ==  1) ? Q2 : 0u;
  return r;
}

// W_aug[o][KTOT]: cols i*8+k = spline_weight[o,i,k]*scaler[o,i]/6 (basis is 6w);
// col 4096+i = base_weight[o,i]
__global__ __launch_bounds__(256) void kan_prep_w(
    const float* __restrict__ bw, const float* __restrict__ sw,
    const float* __restrict__ sc, unsigned short* __restrict__ W) {
  int idx = blockIdx.x * 256 + threadIdx.x;   // o*512 + i
  float scv = sc[idx] * (1.0f / 6.0f);
  float4 s0 = ((const float4*)sw)[idx * 2 + 0];
  float4 s1 = ((const float4*)sw)[idx * 2 + 1];
  unsigned short v[8];
  v[0] = f2bf(s0.x * scv); v[1] = f2bf(s0.y * scv);
  v[2] = f2bf(s0.z * scv); v[3] = f2bf(s0.w * scv);
  v[4] = f2bf(s1.x * scv); v[5] = f2bf(s1.y * scv);
  v[6] = f2bf(s1.z * scv); v[7] = f2bf(s1.w * scv);
  int o = idx >> 9, i = idx & 511;
  *(bf16x8*)(W + (size_t)o * KTOT + i * NB) = *(bf16x8*)v;
  W[(size_t)o * KTOT + KSP + i] = f2bf(bw[idx]);
}

// Phase-2 fragment compute on the XOR-swizzled As layout: element (row, seg s)
// lives at seg s^(row&7). 64x128 per wave: av[4] x bv[8].
__device__ __forceinline__ void mfma_chunk(
    const unsigned short* As, const unsigned short* Bs,
    f32x4 acc[4][8], int wm, int wn, int frow, int quad) {
  const int fr7 = frow & 7;
  #pragma unroll
  for (int ks = 0; ks < 2; ++ks) {
    bf16x8 av[4], bv[8];
    const int sa = ((ks * 4 + quad) ^ fr7) * 8;
    #pragma unroll
    for (int f = 0; f < 4; ++f)
      av[f] = *(const bf16x8*)&As[(wm + f * 16 + frow) * 64 + sa];
    #pragma unroll
    for (int g = 0; g < 8; ++g)
      bv[g] = *(const bf16x8*)&Bs[(wn + g * 16 + frow) * 64 + sa];
    #pragma unroll
    for (int mf = 0; mf < 4; ++mf)
      #pragma unroll
      for (int nf = 0; nf < 8; ++nf)
        acc[mf][nf] = __builtin_amdgcn_mfma_f32_16x16x32_bf16(
            av[mf], bv[nf], acc[mf][nf], 0, 0, 0);
  }
}

// Fused out = A_aug(x) @ W_aug^T. 128(M) x 256(N) tile per 256-thread block.
// Phase 1 (64 spline chunks): A-fragments built IN REGISTERS (R4-verified
// mapping) from a tiny LDS x-tile (128x8 f32 = 4 KB, coalesced float4 stage,
// double-buffered). Eliminates the As write+read burst (-47% phase-1 LDS
// traffic) and needs only ONE barrier per chunk (Bs double-buffered, GLL16
// gets full-chunk cover before the barrier's implicit vmcnt(0) drain).
// Cost: basis VALU x2 (runs in the MFMA shadow; VALU pipe has headroom).
// No setprio / sched pins / asm waits - R1-R5 showed they only hurt here.
// Phase 2 (8 silu chunks): R0's As-staged form (pool reused as As).
__global__ __launch_bounds__(256, 2) void kan_fused(
    const float* __restrict__ x, const unsigned short* __restrict__ W,
    float* __restrict__ out) {
  __shared__ __align__(16) unsigned short Bs[2][256 * 64];   // 64 KB dbuf
  __shared__ __align__(16) unsigned char pool[16384];        // 16 KB shared
  float* xs = (float*)pool;                   // [2][128*8] f32 (phase 1)
  unsigned short* As = (unsigned short*)pool; // [128*64] bf16 (phase 2)

  const int tid = threadIdx.x;
  const int wave = tid >> 6;
  const int lane = tid & 63;
  const int frow = lane & 15;
  const int quad = lane >> 4;
  const int lr = lane >> 3;     // row within 8-row group (staging)
  const int lc = lane & 7;      // 16B-segment / input within group (staging)
  // ntile-siblings 256 apart -> same XCD (round-robin %8) -> x shared in L2
  const int mtile = blockIdx.x & 255;
  const int ntile = blockIdx.x >> 8;          // 0..1
  const int wm = (wave & 1) << 6;
  const int wn = (wave >> 1) << 7;            // 0 or 128
  const int fr7 = frow & 7;

  f32x4 acc[4][8];
  #pragma unroll
  for (int i = 0; i < 4; ++i)
    #pragma unroll
    for (int j = 0; j < 8; ++j)
      acc[i][j] = (f32x4){0.f, 0.f, 0.f, 0.f};

  // B staging base: wave covers 64 rows (8 groups of 8, is-offset is*8*KTOT).
  // Source seg XORed by lr so the lane-linear GLL16 deposit lands swizzled.
  const unsigned short* bg = W +
      (size_t)(ntile * 256 + wave * 64 + lr) * KTOT + ((lc ^ lr) * 8);
  const float* xb = x + (size_t)mtile * 128 * INF;

  // phase-1 x staging: thread t stages row t>>1, cols (t&1)*4 .. +3 (float4)
  const int srow = tid >> 1;
  const int scol = (tid & 1) * 4;
  const float* xsrc = xb + (size_t)srow * INF + scol;

  // ---- Prologue: GLL B(0) -> Bs[0]; x(chunk 0) -> xs[0] ----
  {
    #pragma unroll
    for (int is = 0; is < 8; ++is)
      GLL16(bg + is * 36864, &Bs[0][(wave * 64 + is * 8) * 64]);
    bg += 64;
    float4 v = *(const float4*)xsrc;
    *(float4*)&xs[srow * 8 + scol] = v;
    __syncthreads();   // drains GLL(0) + publishes xs[0]
  }

  // ---- Phase 1: 64 spline chunks, ONE barrier per chunk ----
  for (int kc = 0; kc < 64; ++kc) {
    // issue next-chunk staging first (full-chunk latency cover);
    // kc=63 stages the first silu chunk (cols 4096..) into Bs[0]
    #pragma unroll
    for (int is = 0; is < 8; ++is)
      GLL16(bg + is * 36864, &Bs[(kc + 1) & 1][(wave * 64 + is * 8) * 64]);
    bg += 64;
    float4 xv4;
    if (kc < 63)
      xv4 = *(const float4*)(xsrc + (kc + 1) * 8);

    const float* xc = &xs[(kc & 1) * 1024];
    const unsigned short* Bc = Bs[kc & 1];
    #pragma unroll
    for (int ks = 0; ks < 2; ++ks) {
      bf16x8 bv[8];
      const int sa = ((ks * 4 + quad) ^ fr7) * 8;
      #pragma unroll
      for (int g = 0; g < 8; ++g)
        bv[g] = *(const bf16x8*)&Bc[(wn + g * 16 + frow) * 64 + sa];
      #pragma unroll
      for (int mf = 0; mf < 4; ++mf) {
        // A-frag for row wm+mf*16+frow, K = (kc*8 + ks*4 + quad)*8 .. +7:
        // exactly the 8 basis slots of input (kc*8+ks*4+quad) (R4-verified).
        float xv = xc[(wm + mf * 16 + frow) * 8 + ks * 4 + quad];
        uint4 ab = kan_basis_vec(xv);
        bf16x8 av = __builtin_bit_cast(bf16x8, ab);
        #pragma unroll
        for (int nf = 0; nf < 8; ++nf)
          acc[mf][nf] = __builtin_amdgcn_mfma_f32_16x16x32_bf16(
              av, bv[nf], acc[mf][nf], 0, 0, 0);
      }
    }
    if (kc < 63)   // write late: x-load latency hidden under the MFMA body
      *(float4*)&xs[((kc + 1) & 1) * 1024 + srow * 8 + scol] = xv4;
    __syncthreads();   // drains GLL(kc+1) (full-chunk cover) + xs write
  }

  // ---- Phase 2: silu chunks 64..71, R0 As-staged form (pool = As) ----
  for (int sc = 0; sc < 8; ++sc) {
    float4 v0[4], v1[4];
    #pragma unroll
    for (int is = 0; is < 4; ++is) {   // v-loads first (oldest)
      const int row = wave * 32 + is * 8 + lr;
      const float* xr = xb + (size_t)row * INF + sc * 64 + lc * 8;
      v0[is] = *(const float4*)xr;
      v1[is] = *(const float4*)(xr + 4);
    }
    if (sc < 7) {
      #pragma unroll
      for (int is = 0; is < 8; ++is)
        GLL16(bg + is * 36864, &Bs[(sc + 1) & 1][(wave * 64 + is * 8) * 64]);
      bg += 64;
    }
    #pragma unroll
    for (int is = 0; is < 4; ++is) {
      const int row = wave * 32 + is * 8 + lr;
      float vv[8] = {v0[is].x, v0[is].y, v0[is].z, v0[is].w,
                     v1[is].x, v1[is].y, v1[is].z, v1[is].w};
      float s[8];
      #pragma unroll
      for (int e = 0; e < 8; ++e)
        s[e] = vv[e] * __builtin_amdgcn_rcpf(1.0f + __expf(-vv[e]));
      uint4 pk;
      pk.x = pack_rn(s[0], s[1]);
      pk.y = pack_rn(s[2], s[3]);
      pk.z = pack_rn(s[4], s[5]);
      pk.w = pack_rn(s[6], s[7]);
      *(uint4*)&As[row * 64 + ((lc ^ lr) * 8)] = pk;
    }
    __syncthreads();   // As visible; GLL(next) drained (short cover, 7x only)
    mfma_chunk(As, Bs[sc & 1], acc, wm, wn, frow, quad);
    __syncthreads();   // readers done before next As overwrite
  }

  // ---- Epilogue ----
  const size_t m0 = (size_t)mtile * 128;
  const int n0 = ntile * 256;
  #pragma unroll
  for (int mf = 0; mf < 4; ++mf)
    #pragma unroll
    for (int nf = 0; nf < 8; ++nf)
      #pragma unroll
      for (int r = 0; r < 4; ++r)
        out[(m0 + wm + mf * 16 + quad * 4 + r) * OUTF + (n0 + wn + nf * 16 + frow)] =
            acc[mf][nf][r];
}

// Correct-but-slow fp32 fallback (only if ws can't hold W_aug: 4.7 MB)
__global__ __launch_bounds__(256) void kan_naive(
    const float* __restrict__ x, const float* __restrict__ bw,
    const float* __restrict__ sw, const float* __restrict__ sc,
    float* __restrict__ out) {
  int idx = blockIdx.x * 256 + threadIdx.x;
  int n = idx >> 9, o = idx & 511;
  const float* xr = x + (size_t)n * INF;
  float acc = 0.f;
  for (int i = 0; i < INF; ++i) {
    float xv = xr[i];
    float sil = xv / (1.0f + __expf(-xv));
    float t = (xv + 6.6f) * (1.0f / 1.2f);
    float cf = floorf(t);
    float u = t - cf;
    int j0 = (int)cf - 3;
    float omu = 1.0f - u;
    float u2 = u * u, u3 = u2 * u;
    float w[4];
    w[0] = (1.0f / 6.0f) * omu * omu * omu;
    w[1] = (1.0f / 6.0f) * (3.0f * u3 - 6.0f * u2 + 4.0f);
    w[2] = (1.0f / 6.0f) * (-3.0f * u3 + 3.0f * u2 + 3.0f * u + 1.0f);
    w[3] = (1.0f / 6.0f) * u3;
    int wi = o * INF + i;
    acc += sil * bw[wi];
    float sp = 0.f;
    #pragma unroll
    for (int m = 0; m < 4; ++m) {
      int j = j0 + m;
      if ((unsigned)j < 8u) sp += w[m] * sw[wi * NB + j];
    }
    acc += sp * sc[wi];
  }
  out[idx] = acc;
}

extern "C" void kernel_launch(void* const* d_in, const int* in_sizes, int n_in,
                              void* d_out, int out_size, void* d_ws, size_t ws_size,
                              hipStream_t stream) {
  const float* x  = (const float*)d_in[0];
  const float* bw = (const float*)d_in[1];
  const float* sw = (const float*)d_in[2];
  const float* sc = (const float*)d_in[3];
  float* out = (float*)d_out;

  const size_t wbytes = (size_t)OUTF * KTOT * 2;    // 4.72 MB
  if (ws_size >= wbytes) {
    unsigned short* W = (unsigned short*)d_ws;
    kan_prep_w<<<(OUTF * INF) / 256, 256, 0, stream>>>(bw, sw, sc, W);
    kan_fused<<<(NSAMP / 128) * (OUTF / 256), 256, 0, stream>>>(x, W, out);
  } else {
    kan_naive<<<(NSAMP * OUTF) / 256, 256, 0, stream>>>(x, bw, sw, sc, out);
  }
}

// Round 7
// 284.375 us; speedup vs baseline: 1.0307x; 1.0307x over previous
//
#include <hip/hip_runtime.h>

#define NSAMP 32768
#define INF 512
#define OUTF 512
#define NB 8            // spline bases per input
#define KSP 4096        // INF * NB (spline columns)
#define KTOT 4608       // KSP + INF (silu columns)

typedef __attribute__((ext_vector_type(8))) short bf16x8;
typedef __attribute__((ext_vector_type(4))) float f32x4;

typedef __attribute__((address_space(1))) void gas_void;
typedef __attribute__((address_space(3))) void las_void;
#define GLL16(g, l) __builtin_amdgcn_global_load_lds( \
    (const gas_void*)(g), (las_void*)(l), 16, 0, 0)

// float -> bf16 round-nearest-even (W prep only)
__device__ __forceinline__ unsigned short f2bf(float f) {
  unsigned int u = __float_as_uint(f);
  u += 0x7fffu + ((u >> 16) & 1u);
  return (unsigned short)(u >> 16);
}

// pack two floats as bf16 pair (round-nearest-up). lo in low 16 bits.
__device__ __forceinline__ unsigned pack_rn(float lo, float hi) {
  return __builtin_amdgcn_perm(__float_as_uint(hi) + 0x8000u,
                               __float_as_uint(lo) + 0x8000u, 0x07060302u);
}

// 8-slot cubic B-spline basis vector, scaled by 6 (the 1/6 is folded into W).
// Branchless; out-of-grid x -> all-zero (matches reference clipping).
__device__ __forceinline__ uint4 kan_basis_vec(float xv) {
  float t = __builtin_fmaf(xv, 1.0f / 1.2f, 5.5f);   // (x+6.6)/1.2
  float cf = floorf(t);
  float u = t - cf;
  int j0 = (int)cf - 3;
  float omu = 1.0f - u;
  float u2 = u * u, u3 = u2 * u;
  float omu2 = omu * omu;
  float w0 = omu2 * omu;                                         // 6*(1/6)omu^3
  float w1 = __builtin_fmaf(3.f, u3, __builtin_fmaf(-6.f, u2, 4.f));
  float w2 = __builtin_fmaf(-3.f, u3,
              __builtin_fmaf(3.f, u2, __builtin_fmaf(3.f, u, 1.f)));
  float w3 = u3;
  unsigned P0 = pack_rn(w0, w1);
  unsigned P1 = pack_rn(w2, w3);
  // 128-bit result = [P1:P0] << (16*j0), bits outside [0,128) dropped.
  int p = j0 & 1;
  unsigned Q0 = p ? (P0 << 16) : P0;
  unsigned Q1 = p ? __builtin_amdgcn_alignbit(P1, P0, 16) : P1;
  unsigned Q2 = p ? (P1 >> 16) : 0u;
  int D = j0 >> 1;
  uint4 r;
  r.x = (D == 0) ? Q0 : (D == -1) ? Q1 : (D == -2) ? Q2 : 0u;
  r.y = (D == 1) ? Q0 : (D ==  0) ? Q1 : (D == -1) ? Q2 : 0u;
  r.z = (D == 2) ? Q0 : (D ==  1) ? Q1 : (D ==  0) ? Q2 : 0u;
  r.w = (D == 3) ? Q0 : (D ==  2) ? Q1 : (D ==  1) ? Q2 : 0u;
  return r;
}

// W_aug[o][KTOT]: cols i*8+k = spline_weight[o,i,k]*scaler[o,i]/6 (basis is 6w);
// col 4096+i = base_weight[o,i]
__global__ __launch_bounds__(256) void kan_prep_w(
    const float* __restrict__ bw, const float* __restrict__ sw,
    const float* __restrict__ sc, unsigned short* __restrict__ W) {
  int idx = blockIdx.x * 256 + threadIdx.x;   // o*512 + i
  float scv = sc[idx] * (1.0f / 6.0f);
  float4 s0 = ((const float4*)sw)[idx * 2 + 0];
  float4 s1 = ((const float4*)sw)[idx * 2 + 1];
  unsigned short v[8];
  v[0] = f2bf(s0.x * scv); v[1] = f2bf(s0.y * scv);
  v[2] = f2bf(s0.z * scv); v[3] = f2bf(s0.w * scv);
  v[4] = f2bf(s1.x * scv); v[5] = f2bf(s1.y * scv);
  v[6] = f2bf(s1.z * scv); v[7] = f2bf(s1.w * scv);
  int o = idx >> 9, i = idx & 511;
  *(bf16x8*)(W + (size_t)o * KTOT + i * NB) = *(bf16x8*)v;
  W[(size_t)o * KTOT + KSP + i] = f2bf(bw[idx]);
}

// Silu-phase fragment compute on the XOR-swizzled As layout: element (row,
// seg s) lives at seg s^(row&7). 64x128 per wave: av[4] x bv[8].
__device__ __forceinline__ void mfma_chunk(
    const unsigned short* As, const unsigned short* Bs,
    f32x4 acc[4][8], int wm, int wn, int frow, int quad) {
  const int fr7 = frow & 7;
  #pragma unroll
  for (int ks = 0; ks < 2; ++ks) {
    bf16x8 av[4], bv[8];
    const int sa = ((ks * 4 + quad) ^ fr7) * 8;
    #pragma unroll
    for (int f = 0; f < 4; ++f)
      av[f] = *(const bf16x8*)&As[(wm + f * 16 + frow) * 64 + sa];
    #pragma unroll
    for (int g = 0; g < 8; ++g)
      bv[g] = *(const bf16x8*)&Bs[(wn + g * 16 + frow) * 64 + sa];
    #pragma unroll
    for (int mf = 0; mf < 4; ++mf)
      #pragma unroll
      for (int nf = 0; nf < 8; ++nf)
        acc[mf][nf] = __builtin_amdgcn_mfma_f32_16x16x32_bf16(
            av[mf], bv[nf], acc[mf][nf], 0, 0, 0);
  }
}

// Fused out = A_aug(x) @ W_aug^T. 128(M) x 256(N) tile per 256-thread block.
// Spline phase: A-fragments built IN REGISTERS (R4/R6-verified k-mapping:
// within-MFMA k = quad*8+j <=> input ks*4+quad). x-tile staged to LDS by
// global_load_lds (lane-linear dest, source block-XOR-preswizzled by (row&4)
// so eval reads are <=2-way bank aliased = free). All 8 evals hoisted into
// one ILP-8 block (af[8]) ahead of the bv/MFMA section - no per-mf serial
// read->eval->MFMA chain (R6's exposed-latency bug). One __syncthreads per
// step: its implicit vmcnt(0) drains GLLs issued a full step earlier.
// This removes the av-read + A-write LDS bursts (~35% of step LDS traffic),
// dropping LDS below the MFMA floor; eval VALU (8/lane) rides the separate
// VALU pipe under the sibling wave's MFMAs (m114).
// Silu phase (8/72 steps): R0's As-staged form, As aliased over the xs pool.
__global__ __launch_bounds__(256, 2) void kan_fused(
    const float* __restrict__ x, const unsigned short* __restrict__ W,
    float* __restrict__ out) {
  __shared__ __align__(16) unsigned short Bs[2][256 * 64];   // 64 KB dbuf
  __shared__ __align__(16) unsigned char pool[16384];        // 16 KB shared
  float* xs0 = (float*)pool;                  // [128*8] f32 buf0 (spline)
  float* xs1 = xs0 + 1024;                    // buf1
  unsigned short* As = (unsigned short*)pool; // [128*64] bf16 (silu phase)

  const int tid = threadIdx.x;
  const int wave = tid >> 6;
  const int lane = tid & 63;
  const int frow = lane & 15;
  const int quad = lane >> 4;
  const int lr = lane >> 3;     // row within 8-row group (B staging)
  const int lc = lane & 7;      // 16B-segment / input within group
  // ntile-siblings 256 apart -> same XCD (round-robin %8) -> x shared in L2
  const int mtile = blockIdx.x & 255;
  const int ntile = blockIdx.x >> 8;          // 0..1
  const int wm = (wave & 1) << 6;
  const int wn = (wave >> 1) << 7;            // 0 or 128
  const int fr7 = frow & 7;

  f32x4 acc[4][8];
  #pragma unroll
  for (int i = 0; i < 4; ++i)
    #pragma unroll
    for (int j = 0; j < 8; ++j)
      acc[i][j] = (f32x4){0.f, 0.f, 0.f, 0.f};

  // B staging base (R0 pattern). +64 cols/step; after 64 spline steps the
  // pointer sits exactly at the silu columns (KSP).
  const unsigned short* bg = W +
      (size_t)(ntile * 256 + wave * 64 + lr) * KTOT + ((lc ^ lr) * 8);
  const float* xb = x + (size_t)mtile * 128 * INF;

  // xs staging: thread t fills physical slot t*16B of the 4KB buffer
  // (row t>>1, col-block (t&1)*4). Source col-block XORed by (row&4) so the
  // linear deposit lands swizzled; within-block order is untouched (bank
  // layout only cares about 4B slots, not order inside a 16B block).
  const int srow = tid >> 1;
  const float* xsg = xb + (size_t)srow * INF + (((tid & 1) * 4) ^ (srow & 4));
  float* xsd0 = xs0 + wave * 256;   // wave-uniform GLL dest bases
  float* xsd1 = xs1 + wave * 256;

  // eval-read swizzled col offsets (per-lane constants; row&4 == frow&4
  // because wm and mf*16 never touch bit 2)
  const int xo0 = quad ^ (frow & 4);          // ks=0
  const int xo1 = (4 + quad) ^ (frow & 4);    // ks=1

  // ---- Prologue: GLL B(0) -> Bs[0]; GLL x(0) -> xs0 ----
  {
    #pragma unroll
    for (int is = 0; is < 8; ++is)
      GLL16(bg + is * 36864, &Bs[0][(wave * 64 + is * 8) * 64]);
    bg += 64;
    GLL16(xsg, (las_void*)xsd0);
    __syncthreads();   // implicit vmcnt(0): both staged
  }

  // ---- Spline phase: 64 steps, ONE barrier per step ----
  for (int kc = 0; kc < 64; ++kc) {
    // stage step kc+1 (full-step latency cover before next barrier's drain);
    // kc=63 stages the first silu B-chunk (cols 4096..) into Bs[0]
    if (kc < 63)
      GLL16(xsg + (kc + 1) * 8, (las_void*)(((kc + 1) & 1) ? xsd1 : xsd0));
    #pragma unroll
    for (int is = 0; is < 8; ++is)
      GLL16(bg + is * 36864, &Bs[(kc + 1) & 1][(wave * 64 + is * 8) * 64]);
    bg += 64;

    // ILP-8 eval block: 8 conflict-free b32 reads, 8 independent basis chains
    const float* xc = (kc & 1) ? xs1 : xs0;
    uint4 af[8];
    #pragma unroll
    for (int mf = 0; mf < 4; ++mf) {
      const int rb = (wm + mf * 16 + frow) * 8;
      af[mf * 2 + 0] = kan_basis_vec(xc[rb + xo0]);
      af[mf * 2 + 1] = kan_basis_vec(xc[rb + xo1]);
    }

    // MFMA section: bv from LDS, av from af regs (k-mapping: quad*8+j)
    const unsigned short* Bc = Bs[kc & 1];
    #pragma unroll
    for (int ks = 0; ks < 2; ++ks) {
      bf16x8 bv[8];
      const int sa = ((ks * 4 + quad) ^ fr7) * 8;
      #pragma unroll
      for (int g = 0; g < 8; ++g)
        bv[g] = *(const bf16x8*)&Bc[(wn + g * 16 + frow) * 64 + sa];
      #pragma unroll
      for (int mf = 0; mf < 4; ++mf) {
        bf16x8 av = __builtin_bit_cast(bf16x8, af[mf * 2 + ks]);
        #pragma unroll
        for (int nf = 0; nf < 8; ++nf)
          acc[mf][nf] = __builtin_amdgcn_mfma_f32_16x16x32_bf16(
              av, bv[nf], acc[mf][nf], 0, 0, 0);
      }
    }
    __syncthreads();   // publishes Bs[(kc+1)&1] + xs(kc+1); ends xs/Bs reads
  }

  // ---- Silu phase: 8 steps, R0 As-staged form (pool = As; xs dead) ----
  for (int sc = 0; sc < 8; ++sc) {
    float4 v0[4], v1[4];
    #pragma unroll
    for (int is = 0; is < 4; ++is) {   // v-loads first (oldest)
      const int row = wave * 32 + is * 8 + lr;
      const float* xr = xb + (size_t)row * INF + sc * 64 + lc * 8;
      v0[is] = *(const float4*)xr;
      v1[is] = *(const float4*)(xr + 4);
    }
    if (sc < 7) {
      #pragma unroll
      for (int is = 0; is < 8; ++is)
        GLL16(bg + is * 36864, &Bs[(sc + 1) & 1][(wave * 64 + is * 8) * 64]);
      bg += 64;
    }
    #pragma unroll
    for (int is = 0; is < 4; ++is) {
      const int row = wave * 32 + is * 8 + lr;
      float vv[8] = {v0[is].x, v0[is].y, v0[is].z, v0[is].w,
                     v1[is].x, v1[is].y, v1[is].z, v1[is].w};
      float s[8];
      #pragma unroll
      for (int e = 0; e < 8; ++e)
        s[e] = vv[e] * __builtin_amdgcn_rcpf(1.0f + __expf(-vv[e]));
      uint4 pk;
      pk.x = pack_rn(s[0], s[1]);
      pk.y = pack_rn(s[2], s[3]);
      pk.z = pack_rn(s[4], s[5]);
      pk.w = pack_rn(s[6], s[7]);
      *(uint4*)&As[row * 64 + ((lc ^ lr) * 8)] = pk;
    }
    __syncthreads();   // As visible; GLL(next) drained
    mfma_chunk(As, Bs[sc & 1], acc, wm, wn, frow, quad);
    __syncthreads();   // readers done before next As overwrite
  }

  // ---- Epilogue ----
  const size_t m0 = (size_t)mtile * 128;
  const int n0 = ntile * 256;
  #pragma unroll
  for (int mf = 0; mf < 4; ++mf)
    #pragma unroll
    for (int nf = 0; nf < 8; ++nf)
      #pragma unroll
      for (int r = 0; r < 4; ++r)
        out[(m0 + wm + mf * 16 + quad * 4 + r) * OUTF + (n0 + wn + nf * 16 + frow)] =
            acc[mf][nf][r];
}

// Correct-but-slow fp32 fallback (only if ws can't hold W_aug: 4.7 MB)
__global__ __launch_bounds__(256) void kan_naive(
    const float* __restrict__ x, const float* __restrict__ bw,
    const float* __restrict__ sw, const float* __restrict__ sc,
    float* __restrict__ out) {
  int idx = blockIdx.x * 256 + threadIdx.x;
  int n = idx >> 9, o = idx & 511;
  const float* xr = x + (size_t)n * INF;
  float acc = 0.f;
  for (int i = 0; i < INF; ++i) {
    float xv = xr[i];
    float sil = xv / (1.0f + __expf(-xv));
    float t = (xv + 6.6f) * (1.0f / 1.2f);
    float cf = floorf(t);
    float u = t - cf;
    int j0 = (int)cf - 3;
    float omu = 1.0f - u;
    float u2 = u * u, u3 = u2 * u;
    float w[4];
    w[0] = (1.0f / 6.0f) * omu * omu * omu;
    w[1] = (1.0f / 6.0f) * (3.0f * u3 - 6.0f * u2 + 4.0f);
    w[2] = (1.0f / 6.0f) * (-3.0f * u3 + 3.0f * u2 + 3.0f * u + 1.0f);
    w[3] = (1.0f / 6.0f) * u3;
    int wi = o * INF + i;
    acc += sil * bw[wi];
    float sp = 0.f;
    #pragma unroll
    for (int m = 0; m < 4; ++m) {
      int j = j0 + m;
      if ((unsigned)j < 8u) sp += w[m] * sw[wi * NB + j];
    }
    acc += sp * sc[wi];
  }
  out[idx] = acc;
}

extern "C" void kernel_launch(void* const* d_in, const int* in_sizes, int n_in,
                              void* d_out, int out_size, void* d_ws, size_t ws_size,
                              hipStream_t stream) {
  const float* x  = (const float*)d_in[0];
  const float* bw = (const float*)d_in[1];
  const float* sw = (const float*)d_in[2];
  const float* sc = (const float*)d_in[3];
  float* out = (float*)d_out;

  const size_t wbytes = (size_t)OUTF * KTOT * 2;    // 4.72 MB
  if (ws_size >= wbytes) {
    unsigned short* W = (unsigned short*)d_ws;
    kan_prep_w<<<(OUTF * INF) / 256, 256, 0, stream>>>(bw, sw, sc, W);
    kan_fused<<<(NSAMP / 128) * (OUTF / 256), 256, 0, stream>>>(x, W, out);
  } else {
    kan_naive<<<(NSAMP * OUTF) / 256, 256, 0, stream>>>(x, bw, sw, sc, out);
  }
}